// Round 13
// baseline (261.158 us; speedup 1.0000x reference)
//
#include <hip/hip_runtime.h>
#include <cstddef>
#include <cstdint>

typedef unsigned short ushort_t;
typedef unsigned long long ull_t;
typedef __attribute__((ext_vector_type(8))) short short8;
typedef __attribute__((ext_vector_type(4))) float f32x4;

constexpr int D_ = 512, K_ = 8192, N_ = 16384;
constexpr float MARGIN = 0.75f;   // >= 2*eps of bf16-MFMA score error (max-tail ~0.45)

// RNE float->bf16 (data has no NaN)
__device__ __forceinline__ ushort_t f2bf(float f) {
  unsigned u = __float_as_uint(f);
  return (ushort_t)((u + 0x7FFFu + ((u >> 16) & 1u)) >> 16);
}
// order-preserving float->uint flip (max-compatible)
__device__ __forceinline__ unsigned flipf(float s) {
  unsigned u = __float_as_uint(s);
  return (u & 0x80000000u) ? ~u : (u | 0x80000000u);
}
__device__ __forceinline__ float unflipf(unsigned m) {
  unsigned u = (m & 0x80000000u) ? (m ^ 0x80000000u) : ~m;
  return __uint_as_float(u);
}
__device__ __forceinline__ ull_t umax64(ull_t a, ull_t b) { return a > b ? a : b; }
__device__ __forceinline__ ull_t umin64(ull_t a, ull_t b) { return a < b ? a : b; }

__device__ __forceinline__ void gld16(void* l, const void* g) {
  __builtin_amdgcn_global_load_lds((const __attribute__((address_space(1))) void*)g,
                                   (__attribute__((address_space(3))) void*)l, 16, 0, 0);
}

// -------- fused convert: x and e -> bf16 permuted layout (+ehs), coalesced reads --------
// dst layout per 256-row tile: [g(16)][kq(4)][r(256)] 16B chunks (tile stride 262144 B).
// blocks 0..1023: x rows; blocks 1024..1535: e rows (cols of the score matrix)
__global__ __launch_bounds__(256) void conv_all(const float* __restrict__ x,
                                                const float* __restrict__ e,
                                                char* __restrict__ xbt, char* __restrict__ ebt,
                                                float* __restrict__ ehs) {
  const int g = threadIdx.x & 15, rr = threadIdx.x >> 4;
  if ((int)blockIdx.x < 1024) {
    const int row = blockIdx.x * 16 + rr;
    const float4* src = (const float4*)(x + (size_t)row * D_ + g * 32);
    float4 f[8];
#pragma unroll
    for (int q = 0; q < 8; ++q) f[q] = src[q];
    char* dbase = xbt + (size_t)(row >> 8) * 262144 + g * 16384 + (row & 255) * 16;
#pragma unroll
    for (int kq = 0; kq < 4; ++kq) {
      float4 a = f[kq * 2], b = f[kq * 2 + 1];
      short8 v;
      v[0] = (short)f2bf(a.x); v[1] = (short)f2bf(a.y); v[2] = (short)f2bf(a.z); v[3] = (short)f2bf(a.w);
      v[4] = (short)f2bf(b.x); v[5] = (short)f2bf(b.y); v[6] = (short)f2bf(b.z); v[7] = (short)f2bf(b.w);
      *(short8*)(dbase + kq * 4096) = v;
    }
  } else {
    const int col = (blockIdx.x - 1024) * 16 + rr;
    const float4* src = (const float4*)(e + (size_t)col * D_ + g * 32);
    float4 f[8];
    float ss = 0.f;
#pragma unroll
    for (int q = 0; q < 8; ++q) {
      f[q] = src[q];
      ss += f[q].x * f[q].x + f[q].y * f[q].y + f[q].z * f[q].z + f[q].w * f[q].w;
    }
    char* dbase = ebt + (size_t)(col >> 8) * 262144 + g * 16384 + (col & 255) * 16;
#pragma unroll
    for (int kq = 0; kq < 4; ++kq) {
      float4 a = f[kq * 2], b = f[kq * 2 + 1];
      short8 v;
      v[0] = (short)f2bf(a.x); v[1] = (short)f2bf(a.y); v[2] = (short)f2bf(a.z); v[3] = (short)f2bf(a.w);
      v[4] = (short)f2bf(b.x); v[5] = (short)f2bf(b.y); v[6] = (short)f2bf(b.z); v[7] = (short)f2bf(b.w);
      *(short8*)(dbase + kq * 4096) = v;
    }
#pragma unroll
    for (int m = 1; m < 16; m <<= 1) ss += __shfl_xor(ss, m);
    if (g == 0) ehs[col] = 0.5f * ss;
  }
}

// -------- MFMA scoring: 256x256 tile, 8 waves (2Mx4N), BK=32, dbuf + __syncthreads --------
// per (row, 256-col block): packed top-1 (score|invcol) + s2. grid (64,32), XCD-swizzled.
__global__ __launch_bounds__(512, 2) void dist_mfma(const char* __restrict__ xbt,
                                                    const char* __restrict__ ebt,
                                                    const float* __restrict__ ehs,
                                                    ull_t* __restrict__ ppu,
                                                    float* __restrict__ pps2) {
  __shared__ alignas(16) char lds[65536];   // [buf(2)][A 16K | B 16K]
  const int tid = threadIdx.x, w = tid >> 6, l = tid & 63;
  // XCD-aware bijective remap over 2048 blocks: XCD k owns col-tiles [4k,4k+4)
  const int fid = blockIdx.x + blockIdx.y * 64;
  const int k8 = fid & 7, j = fid >> 3;
  const int by = k8 * 4 + (j & 3), bx = j >> 2;
  const int row0 = bx * 256, col0 = by * 256;
  const int wr = w >> 2, wc = w & 3;
  const char* xsrc = xbt + (size_t)bx * 262144;
  const char* esrc = ebt + (size_t)by * 262144;

  // prologue: stage slab 0 (16KB A + 16KB B) into buf0
#pragma unroll
  for (int i = 0; i < 2; ++i) {
    gld16(lds + i * 8192 + w * 1024, xsrc + i * 8192 + w * 1024 + l * 16);
    gld16(lds + 16384 + i * 8192 + w * 1024, esrc + i * 8192 + w * 1024 + l * 16);
  }
  __syncthreads();

  f32x4 acc[8][4] = {};
  for (int s = 0; s < 16; ++s) {
    char* Ab = lds + (s & 1) * 32768;
    char* Bb = Ab + 16384;
    if (s < 15) {
      char* An = lds + ((s + 1) & 1) * 32768;
#pragma unroll
      for (int i = 0; i < 2; ++i) {
        gld16(An + i * 8192 + w * 1024, xsrc + (s + 1) * 16384 + i * 8192 + w * 1024 + l * 16);
        gld16(An + 16384 + i * 8192 + w * 1024, esrc + (s + 1) * 16384 + i * 8192 + w * 1024 + l * 16);
      }
    }
    const int kq = (l >> 4) * 4096, lc = (l & 15) * 16;
    short8 a[8], b[4];
#pragma unroll
    for (int i = 0; i < 8; ++i)
      a[i] = *(const short8*)(Ab + kq + (wr * 128 + i * 16) * 16 + lc);
#pragma unroll
    for (int jj = 0; jj < 4; ++jj)
      b[jj] = *(const short8*)(Bb + kq + (wc * 64 + jj * 16) * 16 + lc);
#pragma unroll
    for (int i = 0; i < 8; ++i)
#pragma unroll
      for (int jj = 0; jj < 4; ++jj)
        acc[i][jj] = __builtin_amdgcn_mfma_f32_16x16x32_bf16(a[i], b[jj], acc[i][jj], 0, 0, 0);
    __syncthreads();   // drains vm+lgkm: next buffer ready, current buffer free to overwrite
  }

  // ---- epilogue (f32/u32 three-phase per 16-row chunk; 2 owned slots per lane) ----
  float eh[4];
  unsigned ic[4];
#pragma unroll
  for (int jj = 0; jj < 4; ++jj) {
    int col = col0 + wc * 64 + jj * 16 + (l & 15);
    eh[jj] = ehs[col];
    ic[jj] = 0xFFFFFFFFu - (unsigned)col;   // larger == smaller col on score tie; never 0
  }
#pragma unroll
  for (int i = 0; i < 8; ++i)
#pragma unroll
    for (int jj = 0; jj < 4; ++jj)
#pragma unroll
      for (int r = 0; r < 4; ++r)
        acc[i][jj][r] -= eh[jj];

  const int c = l & 15, g16 = l >> 4;
  ull_t fp0 = 0, fp1 = 0;
  float fs20 = -3e38f, fs21 = -3e38f;
#pragma unroll
  for (int i = 0; i < 8; ++i) {
    float mv[4]; unsigned iv[4]; float sv[4];
#pragma unroll
    for (int r = 0; r < 4; ++r)
      mv[r] = fmaxf(fmaxf(acc[i][0][r], acc[i][1][r]), fmaxf(acc[i][2][r], acc[i][3][r]));
#pragma unroll
    for (int m = 1; m < 16; m <<= 1)
#pragma unroll
      for (int r = 0; r < 4; ++r) mv[r] = fmaxf(mv[r], __shfl_xor(mv[r], m));
#pragma unroll
    for (int r = 0; r < 4; ++r) {
      unsigned t0 = (acc[i][0][r] == mv[r]) ? ic[0] : 0u;
      unsigned t1 = (acc[i][1][r] == mv[r]) ? ic[1] : 0u;
      unsigned t2 = (acc[i][2][r] == mv[r]) ? ic[2] : 0u;
      unsigned t3 = (acc[i][3][r] == mv[r]) ? ic[3] : 0u;
      unsigned u01 = t0 > t1 ? t0 : t1, u23 = t2 > t3 ? t2 : t3;
      iv[r] = u01 > u23 ? u01 : u23;
    }
#pragma unroll
    for (int m = 1; m < 16; m <<= 1)
#pragma unroll
      for (int r = 0; r < 4; ++r) {
        unsigned o = __shfl_xor(iv[r], m);
        iv[r] = iv[r] > o ? iv[r] : o;
      }
#pragma unroll
    for (int r = 0; r < 4; ++r) {
      float t0 = (ic[0] == iv[r]) ? -3e38f : acc[i][0][r];
      float t1 = (ic[1] == iv[r]) ? -3e38f : acc[i][1][r];
      float t2 = (ic[2] == iv[r]) ? -3e38f : acc[i][2][r];
      float t3 = (ic[3] == iv[r]) ? -3e38f : acc[i][3][r];
      sv[r] = fmaxf(fmaxf(t0, t1), fmaxf(t2, t3));
    }
#pragma unroll
    for (int m = 1; m < 16; m <<= 1)
#pragma unroll
      for (int r = 0; r < 4; ++r) sv[r] = fmaxf(sv[r], __shfl_xor(sv[r], m));

    if ((c >> 1) == i) {
      const int rb = (c & 1) * 2;
      float m0 = (rb == 0) ? mv[0] : mv[2];
      float m1 = (rb == 0) ? mv[1] : mv[3];
      unsigned i0 = (rb == 0) ? iv[0] : iv[2];
      unsigned i1 = (rb == 0) ? iv[1] : iv[3];
      float q0 = (rb == 0) ? sv[0] : sv[2];
      float q1 = (rb == 0) ? sv[1] : sv[3];
      fp0 = ((ull_t)flipf(m0) << 32) | i0; fs20 = q0;
      fp1 = ((ull_t)flipf(m1) << 32) | i1; fs21 = q1;
    }
  }
  const int iOwn = c >> 1;
  const int rr0 = wr * 128 + iOwn * 16 + g16 * 4 + (c & 1) * 2;  // owned rows in [0,256)

  // cross-wave (wc) merge via LDS (staging area dead after final __syncthreads)
  ull_t* lp = (ull_t*)lds;              // [4][256] = 8KB
  float* ls2 = (float*)(lds + 8192);    // [4][256] = 4KB
  lp[wc * 256 + rr0] = fp0; lp[wc * 256 + rr0 + 1] = fp1;
  ls2[wc * 256 + rr0] = fs20; ls2[wc * 256 + rr0 + 1] = fs21;
  __syncthreads();
  if (tid < 256) {
    ull_t fpm = lp[tid];
    float s2m = ls2[tid];
#pragma unroll
    for (int q = 1; q < 4; ++q) {
      ull_t op = lp[q * 256 + tid];
      float os2 = ls2[q * 256 + tid];
      ull_t lo = umin64(fpm, op);
      s2m = fmaxf(fmaxf(s2m, os2), unflipf((unsigned)(lo >> 32)));
      fpm = umax64(fpm, op);
    }
    ppu[(size_t)(row0 + tid) * 32 + by] = fpm;
    pps2[(size_t)(row0 + tid) * 32 + by] = s2m;
  }
}

// -------- finalize: combine + in-wave exact rescore + gather, one wave per row --------
__global__ __launch_bounds__(256) void finalize(const float* __restrict__ x,
                                                const float* __restrict__ embed,
                                                const float* __restrict__ ehs,
                                                const ull_t* __restrict__ ppu,
                                                const float* __restrict__ pps2,
                                                float* __restrict__ out) {
  const int row = (blockIdx.x * 256 + threadIdx.x) >> 6;
  const int l = threadIdx.x & 63;
  ull_t p = 0;
  float s2 = -3e38f;
  if (l < 32) { p = ppu[(size_t)row * 32 + l]; s2 = pps2[(size_t)row * 32 + l]; }
  ull_t gp = p;
#pragma unroll
  for (int m = 1; m < 64; m <<= 1) gp = umax64(gp, __shfl_xor(gp, m));
  float gs = unflipf((unsigned)(gp >> 32));
  float t = gs - MARGIN;
  float s1 = unflipf((unsigned)(p >> 32));
  bool cand = (l < 32) && (s1 >= t);
  bool ovf = (l < 32) && (s2 >= t);
  ull_t b1 = __ballot(cand);
  ull_t b2 = __ballot(ovf);
  int idx;
  if (__popcll(b1) == 1 && b2 == 0ull) {
    // provably exact: every other col's fp32 score < gs - MARGIN + eps <= winner's fp32 score
    idx = (int)(0xFFFFFFFFu - (unsigned)(gp & 0xFFFFFFFFu));
  } else {
    const float4* xr4 = (const float4*)(x + (size_t)row * D_ + l * 8);
    float4 xa = xr4[0], xc = xr4[1];
    ull_t best = 0ull;
    ull_t bb = b1;
    while (bb) {                       // exact-score each candidate block-top-1 col
      int b = (int)__builtin_ctzll(bb);
      bb &= bb - 1;
      ull_t pb = __shfl(p, b);
      int col = (int)(0xFFFFFFFFu - (unsigned)(pb & 0xFFFFFFFFu));
      const float4* er4 = (const float4*)(embed + (size_t)col * D_ + l * 8);
      float4 ea = er4[0], ec = er4[1];
      float s = xa.x * ea.x + xa.y * ea.y + xa.z * ea.z + xa.w * ea.w
              + xc.x * ec.x + xc.y * ec.y + xc.z * ec.z + xc.w * ec.w;
#pragma unroll
      for (int m = 1; m < 64; m <<= 1) s += __shfl_xor(s, m);
      s -= ehs[col];
      best = umax64(best, ((ull_t)flipf(s) << 32) | (0xFFFFFFFFu - (unsigned)col));
    }
    while (b2) {                       // full exact scan of s2-overflow 256-col blocks (rare)
      int b = (int)__builtin_ctzll(b2);
      b2 &= b2 - 1;
      int c0 = b * 256;
      const float* xr = x + (size_t)row * D_;
      const float* e0p = embed + (size_t)(c0 + l) * D_;
      const float* e1p = embed + (size_t)(c0 + 64 + l) * D_;
      const float* e2p = embed + (size_t)(c0 + 128 + l) * D_;
      const float* e3p = embed + (size_t)(c0 + 192 + l) * D_;
      float a0 = 0.f, a1 = 0.f, a2 = 0.f, a3 = 0.f;
      for (int d = 0; d < D_; d += 4) {
        float4 xv = *(const float4*)(xr + d);
        float4 v0 = *(const float4*)(e0p + d);
        float4 v1 = *(const float4*)(e1p + d);
        float4 v2 = *(const float4*)(e2p + d);
        float4 v3 = *(const float4*)(e3p + d);
        a0 = fmaf(v0.x, xv.x, fmaf(v0.y, xv.y, fmaf(v0.z, xv.z, fmaf(v0.w, xv.w, a0))));
        a1 = fmaf(v1.x, xv.x, fmaf(v1.y, xv.y, fmaf(v1.z, xv.z, fmaf(v1.w, xv.w, a1))));
        a2 = fmaf(v2.x, xv.x, fmaf(v2.y, xv.y, fmaf(v2.z, xv.z, fmaf(v2.w, xv.w, a2))));
        a3 = fmaf(v3.x, xv.x, fmaf(v3.y, xv.y, fmaf(v3.z, xv.z, fmaf(v3.w, xv.w, a3))));
      }
      ull_t pk = ((ull_t)flipf(a0 - ehs[c0 + l]) << 32) | (0xFFFFFFFFu - (unsigned)(c0 + l));
      pk = umax64(pk, ((ull_t)flipf(a1 - ehs[c0 + 64 + l]) << 32) | (0xFFFFFFFFu - (unsigned)(c0 + 64 + l)));
      pk = umax64(pk, ((ull_t)flipf(a2 - ehs[c0 + 128 + l]) << 32) | (0xFFFFFFFFu - (unsigned)(c0 + 128 + l)));
      pk = umax64(pk, ((ull_t)flipf(a3 - ehs[c0 + 192 + l]) << 32) | (0xFFFFFFFFu - (unsigned)(c0 + 192 + l)));
#pragma unroll
      for (int m = 1; m < 64; m <<= 1) pk = umax64(pk, __shfl_xor(pk, m));
      best = umax64(best, pk);
    }
    idx = (int)(0xFFFFFFFFu - (unsigned)(best & 0xFFFFFFFFu));
  }
  const float4* src = (const float4*)(embed + (size_t)idx * D_);
  float4* dst = (float4*)(out + (size_t)row * D_);
  dst[l] = src[l];
  dst[l + 64] = src[l + 64];
  if (l == 0) out[(size_t)N_ * D_ + row] = (float)idx;
}

extern "C" void kernel_launch(void* const* d_in, const int* in_sizes, int n_in,
                              void* d_out, int out_size, void* d_ws, size_t ws_size,
                              hipStream_t stream) {
  const float* x = (const float*)d_in[0];     // [16384, 512]
  const float* e = (const float*)d_in[1];     // [8192, 512]
  float* out = (float*)d_out;

  char* ws = (char*)d_ws;
  char* xbt = ws;                                       // 16 MB (64 tiles x 256 rows)
  char* ebt = ws + 16777216;                            // 8 MB (32 tiles x 256 cols)
  float* ehs = (float*)(ws + 25165824);                 // 32 KB
  ull_t* ppu = (ull_t*)(ws + 25198592);                 // 4 MB (N_*32 ull)
  float* pps2 = (float*)(ws + 29392896);                // 2 MB (N_*32 float)

  conv_all<<<1536, 256, 0, stream>>>(x, e, xbt, ebt, ehs);
  dist_mfma<<<dim3(64, 32), 512, 0, stream>>>(xbt, ebt, ehs, ppu, pps2);
  finalize<<<4096, 256, 0, stream>>>(x, e, ehs, ppu, pps2, out);
}

// Round 14
// 243.304 us; speedup vs baseline: 1.0734x; 1.0734x over previous
//
#include <hip/hip_runtime.h>
#include <cstddef>
#include <cstdint>

typedef unsigned short ushort_t;
typedef unsigned long long ull_t;
typedef __attribute__((ext_vector_type(8))) short short8;
typedef __attribute__((ext_vector_type(4))) float f32x4;

constexpr int D_ = 512, K_ = 8192, N_ = 16384;
constexpr float MARGIN = 0.75f;   // >= 2*eps of bf16-MFMA score error (max-tail ~0.45)

// RNE float->bf16 (data has no NaN)
__device__ __forceinline__ ushort_t f2bf(float f) {
  unsigned u = __float_as_uint(f);
  return (ushort_t)((u + 0x7FFFu + ((u >> 16) & 1u)) >> 16);
}
// order-preserving float->uint flip (max-compatible)
__device__ __forceinline__ unsigned flipf(float s) {
  unsigned u = __float_as_uint(s);
  return (u & 0x80000000u) ? ~u : (u | 0x80000000u);
}
__device__ __forceinline__ float unflipf(unsigned m) {
  unsigned u = (m & 0x80000000u) ? (m ^ 0x80000000u) : ~m;
  return __uint_as_float(u);
}
__device__ __forceinline__ ull_t umax64(ull_t a, ull_t b) { return a > b ? a : b; }
__device__ __forceinline__ ull_t umin64(ull_t a, ull_t b) { return a < b ? a : b; }

__device__ __forceinline__ void gld16(void* l, const void* g) {
  __builtin_amdgcn_global_load_lds((const __attribute__((address_space(1))) void*)g,
                                   (__attribute__((address_space(3))) void*)l, 16, 0, 0);
}

// -------- fused convert: x and e -> bf16 permuted layout (+ehs), coalesced reads --------
// dst layout: [tile][g(16)][kq(4)][r(128)] 16B chunks.
// blocks 0..1023: x (128 tiles x 8 rowgroups); blocks 1024..1535: e (64 tiles x 8 rowgroups)
__global__ __launch_bounds__(256) void conv_all(const float* __restrict__ x,
                                                const float* __restrict__ e,
                                                char* __restrict__ xbt, char* __restrict__ ebt,
                                                float* __restrict__ ehs) {
  const int g = threadIdx.x & 15, rr = threadIdx.x >> 4;
  if ((int)blockIdx.x < 1024) {
    const int tile = blockIdx.x >> 3, rg = blockIdx.x & 7;
    const int r = rg * 16 + rr;
    const float4* src = (const float4*)(x + ((size_t)(tile * 128 + r)) * D_ + g * 32);
    float4 f[8];
#pragma unroll
    for (int q = 0; q < 8; ++q) f[q] = src[q];
    char* dbase = xbt + (size_t)tile * 131072 + g * 8192 + r * 16;
#pragma unroll
    for (int kq = 0; kq < 4; ++kq) {
      float4 a = f[kq * 2], b = f[kq * 2 + 1];
      short8 v;
      v[0] = (short)f2bf(a.x); v[1] = (short)f2bf(a.y); v[2] = (short)f2bf(a.z); v[3] = (short)f2bf(a.w);
      v[4] = (short)f2bf(b.x); v[5] = (short)f2bf(b.y); v[6] = (short)f2bf(b.z); v[7] = (short)f2bf(b.w);
      *(short8*)(dbase + kq * 2048) = v;
    }
  } else {
    const int bid = blockIdx.x - 1024;
    const int tile = bid >> 3, rg = bid & 7;
    const int r = rg * 16 + rr;
    const int col = tile * 128 + r;
    const float4* src = (const float4*)(e + (size_t)col * D_ + g * 32);
    float4 f[8];
    float ss = 0.f;
#pragma unroll
    for (int q = 0; q < 8; ++q) {
      f[q] = src[q];
      ss += f[q].x * f[q].x + f[q].y * f[q].y + f[q].z * f[q].z + f[q].w * f[q].w;
    }
    char* dbase = ebt + (size_t)tile * 131072 + g * 8192 + r * 16;
#pragma unroll
    for (int kq = 0; kq < 4; ++kq) {
      float4 a = f[kq * 2], b = f[kq * 2 + 1];
      short8 v;
      v[0] = (short)f2bf(a.x); v[1] = (short)f2bf(a.y); v[2] = (short)f2bf(a.z); v[3] = (short)f2bf(a.w);
      v[4] = (short)f2bf(b.x); v[5] = (short)f2bf(b.y); v[6] = (short)f2bf(b.z); v[7] = (short)f2bf(b.w);
      *(short8*)(dbase + kq * 2048) = v;
    }
#pragma unroll
    for (int m = 1; m < 16; m <<= 1) ss += __shfl_xor(ss, m);
    if (g == 0) ehs[col] = 0.5f * ss;
  }
}

// -------- MFMA scoring: per (row, 128-col block) packed top-1 (score|invcol) + s2 --------
// grid (128,64); XCD-swizzled; BK=32; double-buffered LDS with __syncthreads per K-step.
// __launch_bounds__(256,4): force total regs <=128/thread (acc=64 AGPR + ~60 VGPR) so
// 4 blocks/CU co-reside — adjacent blocks' compute hides a block's barrier vmcnt drain.
__global__ __launch_bounds__(256, 4) void dist_mfma(const char* __restrict__ xbt,
                                                    const char* __restrict__ ebt,
                                                    const float* __restrict__ ehs,
                                                    ull_t* __restrict__ ppu,
                                                    float* __restrict__ pps2) {
  __shared__ alignas(16) char lds[32768];   // [buf(2)][A(8K)|B(8K)]
  const int tid = threadIdx.x, w = tid >> 6, l = tid & 63;
  // XCD-aware bijective remap: XCD k owns col-tiles [8k,8k+8), sweeps them innermost
  const int fid = blockIdx.x + blockIdx.y * 128;
  const int k8 = fid & 7, j = fid >> 3;
  const int by = k8 * 8 + (j & 7), bx = j >> 3;
  const int row0 = bx * 128, col0 = by * 128;
  const int wr = w >> 1, wc = w & 1;
  const char* xsrc = xbt + (size_t)bx * 131072;
  const char* esrc = ebt + (size_t)by * 131072;

  // prologue: stage slab 0 into buf0 (4 loads/wave)
#pragma unroll
  for (int i = 0; i < 2; ++i) {
    gld16(lds + w * 2048 + i * 1024, xsrc + w * 2048 + i * 1024 + l * 16);
    gld16(lds + 8192 + w * 2048 + i * 1024, esrc + w * 2048 + i * 1024 + l * 16);
  }
  __syncthreads();

  f32x4 acc[4][4] = {};
  for (int g = 0; g < 16; ++g) {
    char* cbase = lds + (g & 1) * 16384;
    // prefetch next slab into the other buffer (flies during ds_read+MFMA below)
    if (g < 15) {
      char* nbase = lds + ((g + 1) & 1) * 16384;
#pragma unroll
      for (int i = 0; i < 2; ++i) {
        gld16(nbase + w * 2048 + i * 1024, xsrc + (g + 1) * 8192 + w * 2048 + i * 1024 + l * 16);
        gld16(nbase + 8192 + w * 2048 + i * 1024, esrc + (g + 1) * 8192 + w * 2048 + i * 1024 + l * 16);
      }
    }
    short8 a[4], b[4];
#pragma unroll
    for (int i = 0; i < 4; ++i)
      a[i] = *(const short8*)(cbase + (l >> 4) * 2048 + (wr * 64 + i * 16 + (l & 15)) * 16);
#pragma unroll
    for (int jj = 0; jj < 4; ++jj)
      b[jj] = *(const short8*)(cbase + 8192 + (l >> 4) * 2048 + (wc * 64 + jj * 16 + (l & 15)) * 16);
#pragma unroll
    for (int i = 0; i < 4; ++i)
#pragma unroll
      for (int jj = 0; jj < 4; ++jj)
        acc[i][jj] = __builtin_amdgcn_mfma_f32_16x16x32_bf16(a[i], b[jj], acc[i][jj], 0, 0, 0);
    __syncthreads();   // drains vm+lgkm: next buffer ready, current buffer free to overwrite
  }

  // ---- epilogue (f32/u32 three-phase; no u64 until the final pack) ----
  float eh[4];
  unsigned ic[4];
#pragma unroll
  for (int jj = 0; jj < 4; ++jj) {
    int col = col0 + wc * 64 + jj * 16 + (l & 15);
    eh[jj] = ehs[col];
    ic[jj] = 0xFFFFFFFFu - (unsigned)col;   // larger == smaller col on score tie; never 0
  }
#pragma unroll
  for (int i = 0; i < 4; ++i)
#pragma unroll
    for (int jj = 0; jj < 4; ++jj)
#pragma unroll
      for (int r = 0; r < 4; ++r)
        acc[i][jj][r] -= eh[jj];

  // Phase A: row max (all-reduce over the 16 col-lanes)
  float mx[4][4];
#pragma unroll
  for (int i = 0; i < 4; ++i)
#pragma unroll
    for (int r = 0; r < 4; ++r)
      mx[i][r] = fmaxf(fmaxf(acc[i][0][r], acc[i][1][r]), fmaxf(acc[i][2][r], acc[i][3][r]));
#pragma unroll
  for (int m = 1; m < 16; m <<= 1)
#pragma unroll
    for (int i = 0; i < 4; ++i)
#pragma unroll
      for (int r = 0; r < 4; ++r)
        mx[i][r] = fmaxf(mx[i][r], __shfl_xor(mx[i][r], m));

  // Phase B: index (max inverted-col among elements equal to max)
  unsigned ii[4][4];
#pragma unroll
  for (int i = 0; i < 4; ++i)
#pragma unroll
    for (int r = 0; r < 4; ++r) {
      unsigned t0 = (acc[i][0][r] == mx[i][r]) ? ic[0] : 0u;
      unsigned t1 = (acc[i][1][r] == mx[i][r]) ? ic[1] : 0u;
      unsigned t2 = (acc[i][2][r] == mx[i][r]) ? ic[2] : 0u;
      unsigned t3 = (acc[i][3][r] == mx[i][r]) ? ic[3] : 0u;
      unsigned u01 = t0 > t1 ? t0 : t1, u23 = t2 > t3 ? t2 : t3;
      ii[i][r] = u01 > u23 ? u01 : u23;
    }
#pragma unroll
  for (int m = 1; m < 16; m <<= 1)
#pragma unroll
    for (int i = 0; i < 4; ++i)
#pragma unroll
      for (int r = 0; r < 4; ++r) {
        unsigned o = __shfl_xor(ii[i][r], m);
        ii[i][r] = ii[i][r] > o ? ii[i][r] : o;
      }

  // Phase C: s2 = max excluding exactly the chosen instance (ties -> s2 == max -> overflow)
  float s2[4][4];
#pragma unroll
  for (int i = 0; i < 4; ++i)
#pragma unroll
    for (int r = 0; r < 4; ++r) {
      float t0 = (ic[0] == ii[i][r]) ? -3e38f : acc[i][0][r];
      float t1 = (ic[1] == ii[i][r]) ? -3e38f : acc[i][1][r];
      float t2 = (ic[2] == ii[i][r]) ? -3e38f : acc[i][2][r];
      float t3 = (ic[3] == ii[i][r]) ? -3e38f : acc[i][3][r];
      s2[i][r] = fmaxf(fmaxf(t0, t1), fmaxf(t2, t3));
    }
#pragma unroll
  for (int m = 1; m < 16; m <<= 1)
#pragma unroll
    for (int i = 0; i < 4; ++i)
#pragma unroll
      for (int r = 0; r < 4; ++r)
        s2[i][r] = fmaxf(s2[i][r], __shfl_xor(s2[i][r], m));

  // owner-lane selection (compile-time indices only)
  const int c = l & 15, g16 = l >> 4;
  float fs1 = -3e38f, fs2 = -3e38f;
  unsigned fii = 0;
#pragma unroll
  for (int i = 0; i < 4; ++i) {
    if ((c >> 2) == i) {
      int rsel = c & 3;
      fs1 = (rsel == 0) ? mx[i][0] : (rsel == 1) ? mx[i][1] : (rsel == 2) ? mx[i][2] : mx[i][3];
      fii = (rsel == 0) ? ii[i][0] : (rsel == 1) ? ii[i][1] : (rsel == 2) ? ii[i][2] : ii[i][3];
      fs2 = (rsel == 0) ? s2[i][0] : (rsel == 1) ? s2[i][1] : (rsel == 2) ? s2[i][2] : s2[i][3];
    }
  }
  ull_t fp = ((ull_t)flipf(fs1) << 32) | fii;
  const int rib = wr * 64 + (c >> 2) * 16 + g16 * 4 + (c & 3);   // owned row in [0,128)

  // cross-wave (wc) merge via LDS (staging area dead after final __syncthreads)
  ull_t* lp = (ull_t*)lds;              // [2][128]
  float* ls2 = (float*)(lds + 2048);    // [2][128]
  lp[wc * 128 + rib] = fp; ls2[wc * 128 + rib] = fs2;
  __syncthreads();
  if (wc == 0) {
    ull_t op = lp[128 + rib];
    float os2 = ls2[128 + rib];
    ull_t lo = umin64(fp, op);
    fs2 = fmaxf(fmaxf(fs2, os2), unflipf((unsigned)(lo >> 32)));
    fp = umax64(fp, op);
    ppu[(size_t)(row0 + rib) * 64 + by] = fp;
    pps2[(size_t)(row0 + rib) * 64 + by] = fs2;
  }
}

// -------- finalize: combine + in-wave exact rescore + gather, one wave per row --------
__global__ __launch_bounds__(256) void finalize(const float* __restrict__ x,
                                                const float* __restrict__ embed,
                                                const float* __restrict__ ehs,
                                                const ull_t* __restrict__ ppu,
                                                const float* __restrict__ pps2,
                                                float* __restrict__ out) {
  const int row = (blockIdx.x * 256 + threadIdx.x) >> 6;
  const int l = threadIdx.x & 63;
  ull_t p = ppu[(size_t)row * 64 + l];
  float s2 = pps2[(size_t)row * 64 + l];
  ull_t gp = p;
#pragma unroll
  for (int m = 1; m < 64; m <<= 1) gp = umax64(gp, __shfl_xor(gp, m));
  float gs = unflipf((unsigned)(gp >> 32));
  float t = gs - MARGIN;
  bool cand = (unflipf((unsigned)(p >> 32)) >= t);
  bool ovf = (s2 >= t);
  ull_t b1 = __ballot(cand);
  ull_t b2 = __ballot(ovf);
  int idx;
  if (__popcll(b1) == 1 && b2 == 0ull) {
    // provably exact: every other col's fp32 score < gs - MARGIN + eps <= winner's fp32 score
    idx = (int)(0xFFFFFFFFu - (unsigned)(gp & 0xFFFFFFFFu));
  } else {
    const float4* xr4 = (const float4*)(x + (size_t)row * D_ + l * 8);
    float4 xa = xr4[0], xc = xr4[1];
    ull_t best = 0ull;
    ull_t bb = b1;
    while (bb) {                       // exact-score each candidate block-top-1 col
      int b = (int)__builtin_ctzll(bb);
      bb &= bb - 1;
      ull_t pb = __shfl(p, b);
      int col = (int)(0xFFFFFFFFu - (unsigned)(pb & 0xFFFFFFFFu));
      const float4* er4 = (const float4*)(embed + (size_t)col * D_ + l * 8);
      float4 ea = er4[0], ec = er4[1];
      float s = xa.x * ea.x + xa.y * ea.y + xa.z * ea.z + xa.w * ea.w
              + xc.x * ec.x + xc.y * ec.y + xc.z * ec.z + xc.w * ec.w;
#pragma unroll
      for (int m = 1; m < 64; m <<= 1) s += __shfl_xor(s, m);
      s -= ehs[col];
      best = umax64(best, ((ull_t)flipf(s) << 32) | (0xFFFFFFFFu - (unsigned)col));
    }
    while (b2) {                       // full exact scan of s2-overflow blocks (rare)
      int b = (int)__builtin_ctzll(b2);
      b2 &= b2 - 1;
      int c0 = b * 128;
      const float* xr = x + (size_t)row * D_;
      const float* e0p = embed + (size_t)(c0 + l) * D_;
      const float* e1p = embed + (size_t)(c0 + 64 + l) * D_;
      float a0 = 0.f, a1 = 0.f;
      for (int d = 0; d < D_; d += 4) {
        float4 xv = *(const float4*)(xr + d);
        float4 v0 = *(const float4*)(e0p + d);
        float4 v1 = *(const float4*)(e1p + d);
        a0 = fmaf(v0.x, xv.x, fmaf(v0.y, xv.y, fmaf(v0.z, xv.z, fmaf(v0.w, xv.w, a0))));
        a1 = fmaf(v1.x, xv.x, fmaf(v1.y, xv.y, fmaf(v1.z, xv.z, fmaf(v1.w, xv.w, a1))));
      }
      float s0 = a0 - ehs[c0 + l];
      float s1 = a1 - ehs[c0 + 64 + l];
      ull_t p0 = ((ull_t)flipf(s0) << 32) | (0xFFFFFFFFu - (unsigned)(c0 + l));
      ull_t p1 = ((ull_t)flipf(s1) << 32) | (0xFFFFFFFFu - (unsigned)(c0 + 64 + l));
      ull_t pk = umax64(p0, p1);
#pragma unroll
      for (int m = 1; m < 64; m <<= 1) pk = umax64(pk, __shfl_xor(pk, m));
      best = umax64(best, pk);
    }
    idx = (int)(0xFFFFFFFFu - (unsigned)(best & 0xFFFFFFFFu));
  }
  const float4* src = (const float4*)(embed + (size_t)idx * D_);
  float4* dst = (float4*)(out + (size_t)row * D_);
  dst[l] = src[l];
  dst[l + 64] = src[l + 64];
  if (l == 0) out[(size_t)N_ * D_ + row] = (float)idx;
}

extern "C" void kernel_launch(void* const* d_in, const int* in_sizes, int n_in,
                              void* d_out, int out_size, void* d_ws, size_t ws_size,
                              hipStream_t stream) {
  const float* x = (const float*)d_in[0];     // [16384, 512]
  const float* e = (const float*)d_in[1];     // [8192, 512]
  float* out = (float*)d_out;

  char* ws = (char*)d_ws;
  char* xbt = ws;                                       // 16 MB
  char* ebt = ws + 16777216;                            // 8 MB
  float* ehs = (float*)(ws + 25165824);                 // 32 KB
  ull_t* ppu = (ull_t*)(ws + 25198592);                 // 8 MB (N_*64 ull)
  float* pps2 = (float*)(ws + 33587200);                // 4 MB (N_*64 float)

  conv_all<<<1536, 256, 0, stream>>>(x, e, xbt, ebt, ehs);
  dist_mfma<<<dim3(128, 64), 256, 0, stream>>>(xbt, ebt, ehs, ppu, pps2);
  finalize<<<4096, 256, 0, stream>>>(x, e, ehs, ppu, pps2, out);
}

// Round 15
// 215.033 us; speedup vs baseline: 1.2145x; 1.1315x over previous
//
#include <hip/hip_runtime.h>
#include <cstddef>
#include <cstdint>

typedef unsigned short ushort_t;
typedef unsigned long long ull_t;
typedef __attribute__((ext_vector_type(8))) short short8;
typedef __attribute__((ext_vector_type(4))) float f32x4;

constexpr int D_ = 512, K_ = 8192, N_ = 16384;
constexpr float MARGIN = 0.75f;   // >= 2*eps of bf16-MFMA score error (max-tail ~0.45)

// RNE float->bf16 (data has no NaN)
__device__ __forceinline__ ushort_t f2bf(float f) {
  unsigned u = __float_as_uint(f);
  return (ushort_t)((u + 0x7FFFu + ((u >> 16) & 1u)) >> 16);
}
// order-preserving float->uint flip (max-compatible)
__device__ __forceinline__ unsigned flipf(float s) {
  unsigned u = __float_as_uint(s);
  return (u & 0x80000000u) ? ~u : (u | 0x80000000u);
}
__device__ __forceinline__ float unflipf(unsigned m) {
  unsigned u = (m & 0x80000000u) ? (m ^ 0x80000000u) : ~m;
  return __uint_as_float(u);
}
__device__ __forceinline__ ull_t umax64(ull_t a, ull_t b) { return a > b ? a : b; }
__device__ __forceinline__ ull_t umin64(ull_t a, ull_t b) { return a < b ? a : b; }

// -------- fused convert: x and e -> bf16 permuted layout (+ehs), coalesced reads --------
// dst layout: [tile][g(16)][kq(4)][r(128)] 16B chunks.
// blocks 0..1023: x (128 tiles x 8 rowgroups); blocks 1024..1535: e (64 tiles x 8 rowgroups)
__global__ __launch_bounds__(256) void conv_all(const float* __restrict__ x,
                                                const float* __restrict__ e,
                                                char* __restrict__ xbt, char* __restrict__ ebt,
                                                float* __restrict__ ehs) {
  const int g = threadIdx.x & 15, rr = threadIdx.x >> 4;
  if ((int)blockIdx.x < 1024) {
    const int tile = blockIdx.x >> 3, rg = blockIdx.x & 7;
    const int r = rg * 16 + rr;
    const float4* src = (const float4*)(x + ((size_t)(tile * 128 + r)) * D_ + g * 32);
    float4 f[8];
#pragma unroll
    for (int q = 0; q < 8; ++q) f[q] = src[q];
    char* dbase = xbt + (size_t)tile * 131072 + g * 8192 + r * 16;
#pragma unroll
    for (int kq = 0; kq < 4; ++kq) {
      float4 a = f[kq * 2], b = f[kq * 2 + 1];
      short8 v;
      v[0] = (short)f2bf(a.x); v[1] = (short)f2bf(a.y); v[2] = (short)f2bf(a.z); v[3] = (short)f2bf(a.w);
      v[4] = (short)f2bf(b.x); v[5] = (short)f2bf(b.y); v[6] = (short)f2bf(b.z); v[7] = (short)f2bf(b.w);
      *(short8*)(dbase + kq * 2048) = v;
    }
  } else {
    const int bid = blockIdx.x - 1024;
    const int tile = bid >> 3, rg = bid & 7;
    const int r = rg * 16 + rr;
    const int col = tile * 128 + r;
    const float4* src = (const float4*)(e + (size_t)col * D_ + g * 32);
    float4 f[8];
    float ss = 0.f;
#pragma unroll
    for (int q = 0; q < 8; ++q) {
      f[q] = src[q];
      ss += f[q].x * f[q].x + f[q].y * f[q].y + f[q].z * f[q].z + f[q].w * f[q].w;
    }
    char* dbase = ebt + (size_t)tile * 131072 + g * 8192 + r * 16;
#pragma unroll
    for (int kq = 0; kq < 4; ++kq) {
      float4 a = f[kq * 2], b = f[kq * 2 + 1];
      short8 v;
      v[0] = (short)f2bf(a.x); v[1] = (short)f2bf(a.y); v[2] = (short)f2bf(a.z); v[3] = (short)f2bf(a.w);
      v[4] = (short)f2bf(b.x); v[5] = (short)f2bf(b.y); v[6] = (short)f2bf(b.z); v[7] = (short)f2bf(b.w);
      *(short8*)(dbase + kq * 2048) = v;
    }
#pragma unroll
    for (int m = 1; m < 16; m <<= 1) ss += __shfl_xor(ss, m);
    if (g == 0) ehs[col] = 0.5f * ss;
  }
}

// -------- MFMA scoring: per (row, 128-col block) packed top-1 (score|invcol) + s2 --------
// grid (128,64); XCD-swizzled. NO LDS staging, NO K-loop barriers: the permuted layout
// makes every MFMA fragment a contiguous per-lane 16B global load (identical address the
// old gld16 staged), so fragments stream straight from L1/L2. Waves are fully independent
// -> race-free by construction; latency hidden by compiler pipelining + 16 waves/CU TLP.
__global__ __launch_bounds__(256, 4) void dist_mfma(const char* __restrict__ xbt,
                                                    const char* __restrict__ ebt,
                                                    const float* __restrict__ ehs,
                                                    ull_t* __restrict__ ppu,
                                                    float* __restrict__ pps2) {
  __shared__ ull_t lp[256];     // cross-wave merge scratch only (3KB)
  __shared__ float ls2[256];
  const int tid = threadIdx.x, w = tid >> 6, l = tid & 63;
  // XCD-aware bijective remap: XCD k owns col-tiles [8k,8k+8), sweeps them innermost
  const int fid = blockIdx.x + blockIdx.y * 128;
  const int k8 = fid & 7, j = fid >> 3;
  const int by = k8 * 8 + (j & 7), bx = j >> 3;
  const int row0 = bx * 128, col0 = by * 128;
  const int wr = w >> 1, wc = w & 1;
  // per-lane fragment base addresses (same addresses the old LDS path staged+read)
  const char* abase = xbt + (size_t)bx * 131072 + (l >> 4) * 2048 + wr * 1024 + (l & 15) * 16;
  const char* bbase = ebt + (size_t)by * 131072 + (l >> 4) * 2048 + wc * 1024 + (l & 15) * 16;

  f32x4 acc[4][4] = {};
#pragma unroll 4
  for (int g = 0; g < 16; ++g) {
    short8 a[4], b[4];
#pragma unroll
    for (int i = 0; i < 4; ++i)
      a[i] = *(const short8*)(abase + g * 8192 + i * 256);
#pragma unroll
    for (int jj = 0; jj < 4; ++jj)
      b[jj] = *(const short8*)(bbase + g * 8192 + jj * 256);
#pragma unroll
    for (int i = 0; i < 4; ++i)
#pragma unroll
      for (int jj = 0; jj < 4; ++jj)
        acc[i][jj] = __builtin_amdgcn_mfma_f32_16x16x32_bf16(a[i], b[jj], acc[i][jj], 0, 0, 0);
  }

  // ---- epilogue (f32/u32 three-phase; no u64 until the final pack) ----
  float eh[4];
  unsigned ic[4];
#pragma unroll
  for (int jj = 0; jj < 4; ++jj) {
    int col = col0 + wc * 64 + jj * 16 + (l & 15);
    eh[jj] = ehs[col];
    ic[jj] = 0xFFFFFFFFu - (unsigned)col;   // larger == smaller col on score tie; never 0
  }
#pragma unroll
  for (int i = 0; i < 4; ++i)
#pragma unroll
    for (int jj = 0; jj < 4; ++jj)
#pragma unroll
      for (int r = 0; r < 4; ++r)
        acc[i][jj][r] -= eh[jj];

  // Phase A: row max (all-reduce over the 16 col-lanes)
  float mx[4][4];
#pragma unroll
  for (int i = 0; i < 4; ++i)
#pragma unroll
    for (int r = 0; r < 4; ++r)
      mx[i][r] = fmaxf(fmaxf(acc[i][0][r], acc[i][1][r]), fmaxf(acc[i][2][r], acc[i][3][r]));
#pragma unroll
  for (int m = 1; m < 16; m <<= 1)
#pragma unroll
    for (int i = 0; i < 4; ++i)
#pragma unroll
      for (int r = 0; r < 4; ++r)
        mx[i][r] = fmaxf(mx[i][r], __shfl_xor(mx[i][r], m));

  // Phase B: index (max inverted-col among elements equal to max)
  unsigned ii[4][4];
#pragma unroll
  for (int i = 0; i < 4; ++i)
#pragma unroll
    for (int r = 0; r < 4; ++r) {
      unsigned t0 = (acc[i][0][r] == mx[i][r]) ? ic[0] : 0u;
      unsigned t1 = (acc[i][1][r] == mx[i][r]) ? ic[1] : 0u;
      unsigned t2 = (acc[i][2][r] == mx[i][r]) ? ic[2] : 0u;
      unsigned t3 = (acc[i][3][r] == mx[i][r]) ? ic[3] : 0u;
      unsigned u01 = t0 > t1 ? t0 : t1, u23 = t2 > t3 ? t2 : t3;
      ii[i][r] = u01 > u23 ? u01 : u23;
    }
#pragma unroll
  for (int m = 1; m < 16; m <<= 1)
#pragma unroll
    for (int i = 0; i < 4; ++i)
#pragma unroll
      for (int r = 0; r < 4; ++r) {
        unsigned o = __shfl_xor(ii[i][r], m);
        ii[i][r] = ii[i][r] > o ? ii[i][r] : o;
      }

  // Phase C: s2 = max excluding exactly the chosen instance (ties -> s2 == max -> overflow)
  float s2[4][4];
#pragma unroll
  for (int i = 0; i < 4; ++i)
#pragma unroll
    for (int r = 0; r < 4; ++r) {
      float t0 = (ic[0] == ii[i][r]) ? -3e38f : acc[i][0][r];
      float t1 = (ic[1] == ii[i][r]) ? -3e38f : acc[i][1][r];
      float t2 = (ic[2] == ii[i][r]) ? -3e38f : acc[i][2][r];
      float t3 = (ic[3] == ii[i][r]) ? -3e38f : acc[i][3][r];
      s2[i][r] = fmaxf(fmaxf(t0, t1), fmaxf(t2, t3));
    }
#pragma unroll
  for (int m = 1; m < 16; m <<= 1)
#pragma unroll
    for (int i = 0; i < 4; ++i)
#pragma unroll
      for (int r = 0; r < 4; ++r)
        s2[i][r] = fmaxf(s2[i][r], __shfl_xor(s2[i][r], m));

  // owner-lane selection (compile-time indices only)
  const int c = l & 15, g16 = l >> 4;
  float fs1 = -3e38f, fs2 = -3e38f;
  unsigned fii = 0;
#pragma unroll
  for (int i = 0; i < 4; ++i) {
    if ((c >> 2) == i) {
      int rsel = c & 3;
      fs1 = (rsel == 0) ? mx[i][0] : (rsel == 1) ? mx[i][1] : (rsel == 2) ? mx[i][2] : mx[i][3];
      fii = (rsel == 0) ? ii[i][0] : (rsel == 1) ? ii[i][1] : (rsel == 2) ? ii[i][2] : ii[i][3];
      fs2 = (rsel == 0) ? s2[i][0] : (rsel == 1) ? s2[i][1] : (rsel == 2) ? s2[i][2] : s2[i][3];
    }
  }
  ull_t fp = ((ull_t)flipf(fs1) << 32) | fii;
  const int rib = wr * 64 + (c >> 2) * 16 + g16 * 4 + (c & 3);   // owned row in [0,128)

  // cross-wave (wc) merge via LDS
  lp[wc * 128 + rib] = fp; ls2[wc * 128 + rib] = fs2;
  __syncthreads();
  if (wc == 0) {
    ull_t op = lp[128 + rib];
    float os2 = ls2[128 + rib];
    ull_t lo = umin64(fp, op);
    fs2 = fmaxf(fmaxf(fs2, os2), unflipf((unsigned)(lo >> 32)));
    fp = umax64(fp, op);
    ppu[(size_t)(row0 + rib) * 64 + by] = fp;
    pps2[(size_t)(row0 + rib) * 64 + by] = fs2;
  }
}

// -------- finalize: combine + in-wave exact rescore + gather, one wave per row --------
__global__ __launch_bounds__(256) void finalize(const float* __restrict__ x,
                                                const float* __restrict__ embed,
                                                const float* __restrict__ ehs,
                                                const ull_t* __restrict__ ppu,
                                                const float* __restrict__ pps2,
                                                float* __restrict__ out) {
  const int row = (blockIdx.x * 256 + threadIdx.x) >> 6;
  const int l = threadIdx.x & 63;
  ull_t p = ppu[(size_t)row * 64 + l];
  float s2 = pps2[(size_t)row * 64 + l];
  ull_t gp = p;
#pragma unroll
  for (int m = 1; m < 64; m <<= 1) gp = umax64(gp, __shfl_xor(gp, m));
  float gs = unflipf((unsigned)(gp >> 32));
  float t = gs - MARGIN;
  bool cand = (unflipf((unsigned)(p >> 32)) >= t);
  bool ovf = (s2 >= t);
  ull_t b1 = __ballot(cand);
  ull_t b2 = __ballot(ovf);
  int idx;
  if (__popcll(b1) == 1 && b2 == 0ull) {
    // provably exact: every other col's fp32 score < gs - MARGIN + eps <= winner's fp32 score
    idx = (int)(0xFFFFFFFFu - (unsigned)(gp & 0xFFFFFFFFu));
  } else {
    const float4* xr4 = (const float4*)(x + (size_t)row * D_ + l * 8);
    float4 xa = xr4[0], xc = xr4[1];
    ull_t best = 0ull;
    ull_t bb = b1;
    while (bb) {                       // exact-score each candidate block-top-1 col
      int b = (int)__builtin_ctzll(bb);
      bb &= bb - 1;
      ull_t pb = __shfl(p, b);
      int col = (int)(0xFFFFFFFFu - (unsigned)(pb & 0xFFFFFFFFu));
      const float4* er4 = (const float4*)(embed + (size_t)col * D_ + l * 8);
      float4 ea = er4[0], ec = er4[1];
      float s = xa.x * ea.x + xa.y * ea.y + xa.z * ea.z + xa.w * ea.w
              + xc.x * ec.x + xc.y * ec.y + xc.z * ec.z + xc.w * ec.w;
#pragma unroll
      for (int m = 1; m < 64; m <<= 1) s += __shfl_xor(s, m);
      s -= ehs[col];
      best = umax64(best, ((ull_t)flipf(s) << 32) | (0xFFFFFFFFu - (unsigned)col));
    }
    while (b2) {                       // full exact scan of s2-overflow blocks (rare)
      int b = (int)__builtin_ctzll(b2);
      b2 &= b2 - 1;
      int c0 = b * 128;
      const float* xr = x + (size_t)row * D_;
      const float* e0p = embed + (size_t)(c0 + l) * D_;
      const float* e1p = embed + (size_t)(c0 + 64 + l) * D_;
      float a0 = 0.f, a1 = 0.f;
      for (int d = 0; d < D_; d += 4) {
        float4 xv = *(const float4*)(xr + d);
        float4 v0 = *(const float4*)(e0p + d);
        float4 v1 = *(const float4*)(e1p + d);
        a0 = fmaf(v0.x, xv.x, fmaf(v0.y, xv.y, fmaf(v0.z, xv.z, fmaf(v0.w, xv.w, a0))));
        a1 = fmaf(v1.x, xv.x, fmaf(v1.y, xv.y, fmaf(v1.z, xv.z, fmaf(v1.w, xv.w, a1))));
      }
      float s0 = a0 - ehs[c0 + l];
      float s1 = a1 - ehs[c0 + 64 + l];
      ull_t p0 = ((ull_t)flipf(s0) << 32) | (0xFFFFFFFFu - (unsigned)(c0 + l));
      ull_t p1 = ((ull_t)flipf(s1) << 32) | (0xFFFFFFFFu - (unsigned)(c0 + 64 + l));
      ull_t pk = umax64(p0, p1);
#pragma unroll
      for (int m = 1; m < 64; m <<= 1) pk = umax64(pk, __shfl_xor(pk, m));
      best = umax64(best, pk);
    }
    idx = (int)(0xFFFFFFFFu - (unsigned)(best & 0xFFFFFFFFu));
  }
  const float4* src = (const float4*)(embed + (size_t)idx * D_);
  float4* dst = (float4*)(out + (size_t)row * D_);
  dst[l] = src[l];
  dst[l + 64] = src[l + 64];
  if (l == 0) out[(size_t)N_ * D_ + row] = (float)idx;
}

extern "C" void kernel_launch(void* const* d_in, const int* in_sizes, int n_in,
                              void* d_out, int out_size, void* d_ws, size_t ws_size,
                              hipStream_t stream) {
  const float* x = (const float*)d_in[0];     // [16384, 512]
  const float* e = (const float*)d_in[1];     // [8192, 512]
  float* out = (float*)d_out;

  char* ws = (char*)d_ws;
  char* xbt = ws;                                       // 16 MB
  char* ebt = ws + 16777216;                            // 8 MB
  float* ehs = (float*)(ws + 25165824);                 // 32 KB
  ull_t* ppu = (ull_t*)(ws + 25198592);                 // 8 MB (N_*64 ull)
  float* pps2 = (float*)(ws + 33587200);                // 4 MB (N_*64 float)

  conv_all<<<1536, 256, 0, stream>>>(x, e, xbt, ebt, ehs);
  dist_mfma<<<dim3(128, 64), 256, 0, stream>>>(xbt, ebt, ehs, ppu, pps2);
  finalize<<<4096, 256, 0, stream>>>(x, e, ehs, ppu, pps2, out);
}

// Round 16
// 204.415 us; speedup vs baseline: 1.2776x; 1.0519x over previous
//
#include <hip/hip_runtime.h>
#include <cstddef>
#include <cstdint>

typedef unsigned short ushort_t;
typedef unsigned long long ull_t;
typedef __attribute__((ext_vector_type(8))) short short8;
typedef __attribute__((ext_vector_type(4))) float f32x4;

constexpr int D_ = 512, K_ = 8192, N_ = 16384;
constexpr float MARGIN = 0.75f;   // >= 2*eps of bf16-MFMA score error (max-tail ~0.45)

// RNE float->bf16 (data has no NaN)
__device__ __forceinline__ ushort_t f2bf(float f) {
  unsigned u = __float_as_uint(f);
  return (ushort_t)((u + 0x7FFFu + ((u >> 16) & 1u)) >> 16);
}
// order-preserving float->uint flip (max-compatible)
__device__ __forceinline__ unsigned flipf(float s) {
  unsigned u = __float_as_uint(s);
  return (u & 0x80000000u) ? ~u : (u | 0x80000000u);
}
__device__ __forceinline__ float unflipf(unsigned m) {
  unsigned u = (m & 0x80000000u) ? (m ^ 0x80000000u) : ~m;
  return __uint_as_float(u);
}
__device__ __forceinline__ ull_t umax64(ull_t a, ull_t b) { return a > b ? a : b; }
__device__ __forceinline__ ull_t umin64(ull_t a, ull_t b) { return a < b ? a : b; }

// -------- fused convert: x and e -> bf16 permuted layout (+ehs), coalesced reads --------
// dst layout: [tile][g(16)][kq(4)][r(128)] 16B chunks.
// blocks 0..1023: x (128 tiles x 8 rowgroups); blocks 1024..1535: e (64 tiles x 8 rowgroups)
__global__ __launch_bounds__(256) void conv_all(const float* __restrict__ x,
                                                const float* __restrict__ e,
                                                char* __restrict__ xbt, char* __restrict__ ebt,
                                                float* __restrict__ ehs) {
  const int g = threadIdx.x & 15, rr = threadIdx.x >> 4;
  if ((int)blockIdx.x < 1024) {
    const int tile = blockIdx.x >> 3, rg = blockIdx.x & 7;
    const int r = rg * 16 + rr;
    const float4* src = (const float4*)(x + ((size_t)(tile * 128 + r)) * D_ + g * 32);
    float4 f[8];
#pragma unroll
    for (int q = 0; q < 8; ++q) f[q] = src[q];
    char* dbase = xbt + (size_t)tile * 131072 + g * 8192 + r * 16;
#pragma unroll
    for (int kq = 0; kq < 4; ++kq) {
      float4 a = f[kq * 2], b = f[kq * 2 + 1];
      short8 v;
      v[0] = (short)f2bf(a.x); v[1] = (short)f2bf(a.y); v[2] = (short)f2bf(a.z); v[3] = (short)f2bf(a.w);
      v[4] = (short)f2bf(b.x); v[5] = (short)f2bf(b.y); v[6] = (short)f2bf(b.z); v[7] = (short)f2bf(b.w);
      *(short8*)(dbase + kq * 2048) = v;
    }
  } else {
    const int bid = blockIdx.x - 1024;
    const int tile = bid >> 3, rg = bid & 7;
    const int r = rg * 16 + rr;
    const int col = tile * 128 + r;
    const float4* src = (const float4*)(e + (size_t)col * D_ + g * 32);
    float4 f[8];
    float ss = 0.f;
#pragma unroll
    for (int q = 0; q < 8; ++q) {
      f[q] = src[q];
      ss += f[q].x * f[q].x + f[q].y * f[q].y + f[q].z * f[q].z + f[q].w * f[q].w;
    }
    char* dbase = ebt + (size_t)tile * 131072 + g * 8192 + r * 16;
#pragma unroll
    for (int kq = 0; kq < 4; ++kq) {
      float4 a = f[kq * 2], b = f[kq * 2 + 1];
      short8 v;
      v[0] = (short)f2bf(a.x); v[1] = (short)f2bf(a.y); v[2] = (short)f2bf(a.z); v[3] = (short)f2bf(a.w);
      v[4] = (short)f2bf(b.x); v[5] = (short)f2bf(b.y); v[6] = (short)f2bf(b.z); v[7] = (short)f2bf(b.w);
      *(short8*)(dbase + kq * 2048) = v;
    }
#pragma unroll
    for (int m = 1; m < 16; m <<= 1) ss += __shfl_xor(ss, m);
    if (g == 0) ehs[col] = 0.5f * ss;
  }
}

// -------- MFMA scoring: per (row, 128-col block) packed top-1 (score|invcol) + s2 --------
// grid (128,64); XCD-swizzled. Barrier-free streaming K-loop (fragments direct from L1/L2)
// with explicit 1-deep software pipeline: g+1's 8 fragment loads issue BEFORE g's MFMA
// cluster, hiding one g-step of load latency. (256,3) gives the register headroom for the
// double-buffered fragments. setprio(1) favors MFMA-issuing waves (T5, independent-wave
// regime). No inter-wave sync anywhere -> race-free by construction.
__global__ __launch_bounds__(256, 3) void dist_mfma(const char* __restrict__ xbt,
                                                    const char* __restrict__ ebt,
                                                    const float* __restrict__ ehs,
                                                    ull_t* __restrict__ ppu,
                                                    float* __restrict__ pps2) {
  __shared__ ull_t lp[256];     // cross-wave merge scratch only (3KB)
  __shared__ float ls2[256];
  const int tid = threadIdx.x, w = tid >> 6, l = tid & 63;
  // XCD-aware bijective remap: XCD k owns col-tiles [8k,8k+8), sweeps them innermost
  const int fid = blockIdx.x + blockIdx.y * 128;
  const int k8 = fid & 7, j = fid >> 3;
  const int by = k8 * 8 + (j & 7), bx = j >> 3;
  const int row0 = bx * 128, col0 = by * 128;
  const int wr = w >> 1, wc = w & 1;
  // per-lane fragment base addresses (contiguous 16B per lane in the permuted layout)
  const char* abase = xbt + (size_t)bx * 131072 + (l >> 4) * 2048 + wr * 1024 + (l & 15) * 16;
  const char* bbase = ebt + (size_t)by * 131072 + (l >> 4) * 2048 + wc * 1024 + (l & 15) * 16;

  short8 a[2][4], b[2][4];
#pragma unroll
  for (int i = 0; i < 4; ++i) a[0][i] = *(const short8*)(abase + i * 256);
#pragma unroll
  for (int jj = 0; jj < 4; ++jj) b[0][jj] = *(const short8*)(bbase + jj * 256);

  f32x4 acc[4][4] = {};
#pragma unroll
  for (int g = 0; g < 16; ++g) {
    const int cur = g & 1, nxt = cur ^ 1;
    if (g < 15) {
#pragma unroll
      for (int i = 0; i < 4; ++i)
        a[nxt][i] = *(const short8*)(abase + (g + 1) * 8192 + i * 256);
#pragma unroll
      for (int jj = 0; jj < 4; ++jj)
        b[nxt][jj] = *(const short8*)(bbase + (g + 1) * 8192 + jj * 256);
    }
    __builtin_amdgcn_s_setprio(1);
#pragma unroll
    for (int i = 0; i < 4; ++i)
#pragma unroll
      for (int jj = 0; jj < 4; ++jj)
        acc[i][jj] = __builtin_amdgcn_mfma_f32_16x16x32_bf16(a[cur][i], b[cur][jj], acc[i][jj], 0, 0, 0);
    __builtin_amdgcn_s_setprio(0);
  }

  // ---- epilogue (f32/u32 three-phase; no u64 until the final pack) ----
  float eh[4];
  unsigned ic[4];
#pragma unroll
  for (int jj = 0; jj < 4; ++jj) {
    int col = col0 + wc * 64 + jj * 16 + (l & 15);
    eh[jj] = ehs[col];
    ic[jj] = 0xFFFFFFFFu - (unsigned)col;   // larger == smaller col on score tie; never 0
  }
#pragma unroll
  for (int i = 0; i < 4; ++i)
#pragma unroll
    for (int jj = 0; jj < 4; ++jj)
#pragma unroll
      for (int r = 0; r < 4; ++r)
        acc[i][jj][r] -= eh[jj];

  // Phase A: row max (all-reduce over the 16 col-lanes)
  float mx[4][4];
#pragma unroll
  for (int i = 0; i < 4; ++i)
#pragma unroll
    for (int r = 0; r < 4; ++r)
      mx[i][r] = fmaxf(fmaxf(acc[i][0][r], acc[i][1][r]), fmaxf(acc[i][2][r], acc[i][3][r]));
#pragma unroll
  for (int m = 1; m < 16; m <<= 1)
#pragma unroll
    for (int i = 0; i < 4; ++i)
#pragma unroll
      for (int r = 0; r < 4; ++r)
        mx[i][r] = fmaxf(mx[i][r], __shfl_xor(mx[i][r], m));

  // Phase B: index (max inverted-col among elements equal to max)
  unsigned ii[4][4];
#pragma unroll
  for (int i = 0; i < 4; ++i)
#pragma unroll
    for (int r = 0; r < 4; ++r) {
      unsigned t0 = (acc[i][0][r] == mx[i][r]) ? ic[0] : 0u;
      unsigned t1 = (acc[i][1][r] == mx[i][r]) ? ic[1] : 0u;
      unsigned t2 = (acc[i][2][r] == mx[i][r]) ? ic[2] : 0u;
      unsigned t3 = (acc[i][3][r] == mx[i][r]) ? ic[3] : 0u;
      unsigned u01 = t0 > t1 ? t0 : t1, u23 = t2 > t3 ? t2 : t3;
      ii[i][r] = u01 > u23 ? u01 : u23;
    }
#pragma unroll
  for (int m = 1; m < 16; m <<= 1)
#pragma unroll
    for (int i = 0; i < 4; ++i)
#pragma unroll
      for (int r = 0; r < 4; ++r) {
        unsigned o = __shfl_xor(ii[i][r], m);
        ii[i][r] = ii[i][r] > o ? ii[i][r] : o;
      }

  // Phase C: s2 = max excluding exactly the chosen instance (ties -> s2 == max -> overflow)
  float s2[4][4];
#pragma unroll
  for (int i = 0; i < 4; ++i)
#pragma unroll
    for (int r = 0; r < 4; ++r) {
      float t0 = (ic[0] == ii[i][r]) ? -3e38f : acc[i][0][r];
      float t1 = (ic[1] == ii[i][r]) ? -3e38f : acc[i][1][r];
      float t2 = (ic[2] == ii[i][r]) ? -3e38f : acc[i][2][r];
      float t3 = (ic[3] == ii[i][r]) ? -3e38f : acc[i][3][r];
      s2[i][r] = fmaxf(fmaxf(t0, t1), fmaxf(t2, t3));
    }
#pragma unroll
  for (int m = 1; m < 16; m <<= 1)
#pragma unroll
    for (int i = 0; i < 4; ++i)
#pragma unroll
      for (int r = 0; r < 4; ++r)
        s2[i][r] = fmaxf(s2[i][r], __shfl_xor(s2[i][r], m));

  // owner-lane selection (compile-time indices only)
  const int c = l & 15, g16 = l >> 4;
  float fs1 = -3e38f, fs2 = -3e38f;
  unsigned fii = 0;
#pragma unroll
  for (int i = 0; i < 4; ++i) {
    if ((c >> 2) == i) {
      int rsel = c & 3;
      fs1 = (rsel == 0) ? mx[i][0] : (rsel == 1) ? mx[i][1] : (rsel == 2) ? mx[i][2] : mx[i][3];
      fii = (rsel == 0) ? ii[i][0] : (rsel == 1) ? ii[i][1] : (rsel == 2) ? ii[i][2] : ii[i][3];
      fs2 = (rsel == 0) ? s2[i][0] : (rsel == 1) ? s2[i][1] : (rsel == 2) ? s2[i][2] : s2[i][3];
    }
  }
  ull_t fp = ((ull_t)flipf(fs1) << 32) | fii;
  const int rib = wr * 64 + (c >> 2) * 16 + g16 * 4 + (c & 3);   // owned row in [0,128)

  // cross-wave (wc) merge via LDS
  lp[wc * 128 + rib] = fp; ls2[wc * 128 + rib] = fs2;
  __syncthreads();
  if (wc == 0) {
    ull_t op = lp[128 + rib];
    float os2 = ls2[128 + rib];
    ull_t lo = umin64(fp, op);
    fs2 = fmaxf(fmaxf(fs2, os2), unflipf((unsigned)(lo >> 32)));
    fp = umax64(fp, op);
    ppu[(size_t)(row0 + rib) * 64 + by] = fp;
    pps2[(size_t)(row0 + rib) * 64 + by] = fs2;
  }
}

// -------- finalize: combine + in-wave exact rescore + gather, one wave per row --------
__global__ __launch_bounds__(256) void finalize(const float* __restrict__ x,
                                                const float* __restrict__ embed,
                                                const float* __restrict__ ehs,
                                                const ull_t* __restrict__ ppu,
                                                const float* __restrict__ pps2,
                                                float* __restrict__ out) {
  const int row = (blockIdx.x * 256 + threadIdx.x) >> 6;
  const int l = threadIdx.x & 63;
  ull_t p = ppu[(size_t)row * 64 + l];
  float s2 = pps2[(size_t)row * 64 + l];
  ull_t gp = p;
#pragma unroll
  for (int m = 1; m < 64; m <<= 1) gp = umax64(gp, __shfl_xor(gp, m));
  float gs = unflipf((unsigned)(gp >> 32));
  float t = gs - MARGIN;
  bool cand = (unflipf((unsigned)(p >> 32)) >= t);
  bool ovf = (s2 >= t);
  ull_t b1 = __ballot(cand);
  ull_t b2 = __ballot(ovf);
  int idx;
  if (__popcll(b1) == 1 && b2 == 0ull) {
    // provably exact: every other col's fp32 score < gs - MARGIN + eps <= winner's fp32 score
    idx = (int)(0xFFFFFFFFu - (unsigned)(gp & 0xFFFFFFFFu));
  } else {
    const float4* xr4 = (const float4*)(x + (size_t)row * D_ + l * 8);
    float4 xa = xr4[0], xc = xr4[1];
    ull_t best = 0ull;
    ull_t bb = b1;
    while (bb) {                       // exact-score each candidate block-top-1 col
      int b = (int)__builtin_ctzll(bb);
      bb &= bb - 1;
      ull_t pb = __shfl(p, b);
      int col = (int)(0xFFFFFFFFu - (unsigned)(pb & 0xFFFFFFFFu));
      const float4* er4 = (const float4*)(embed + (size_t)col * D_ + l * 8);
      float4 ea = er4[0], ec = er4[1];
      float s = xa.x * ea.x + xa.y * ea.y + xa.z * ea.z + xa.w * ea.w
              + xc.x * ec.x + xc.y * ec.y + xc.z * ec.z + xc.w * ec.w;
#pragma unroll
      for (int m = 1; m < 64; m <<= 1) s += __shfl_xor(s, m);
      s -= ehs[col];
      best = umax64(best, ((ull_t)flipf(s) << 32) | (0xFFFFFFFFu - (unsigned)col));
    }
    while (b2) {                       // full exact scan of s2-overflow blocks (rare)
      int b = (int)__builtin_ctzll(b2);
      b2 &= b2 - 1;
      int c0 = b * 128;
      const float* xr = x + (size_t)row * D_;
      const float* e0p = embed + (size_t)(c0 + l) * D_;
      const float* e1p = embed + (size_t)(c0 + 64 + l) * D_;
      float a0 = 0.f, a1 = 0.f;
      for (int d = 0; d < D_; d += 4) {
        float4 xv = *(const float4*)(xr + d);
        float4 v0 = *(const float4*)(e0p + d);
        float4 v1 = *(const float4*)(e1p + d);
        a0 = fmaf(v0.x, xv.x, fmaf(v0.y, xv.y, fmaf(v0.z, xv.z, fmaf(v0.w, xv.w, a0))));
        a1 = fmaf(v1.x, xv.x, fmaf(v1.y, xv.y, fmaf(v1.z, xv.z, fmaf(v1.w, xv.w, a1))));
      }
      float s0 = a0 - ehs[c0 + l];
      float s1 = a1 - ehs[c0 + 64 + l];
      ull_t p0 = ((ull_t)flipf(s0) << 32) | (0xFFFFFFFFu - (unsigned)(c0 + l));
      ull_t p1 = ((ull_t)flipf(s1) << 32) | (0xFFFFFFFFu - (unsigned)(c0 + 64 + l));
      ull_t pk = umax64(p0, p1);
#pragma unroll
      for (int m = 1; m < 64; m <<= 1) pk = umax64(pk, __shfl_xor(pk, m));
      best = umax64(best, pk);
    }
    idx = (int)(0xFFFFFFFFu - (unsigned)(best & 0xFFFFFFFFu));
  }
  const float4* src = (const float4*)(embed + (size_t)idx * D_);
  float4* dst = (float4*)(out + (size_t)row * D_);
  dst[l] = src[l];
  dst[l + 64] = src[l + 64];
  if (l == 0) out[(size_t)N_ * D_ + row] = (float)idx;
}

extern "C" void kernel_launch(void* const* d_in, const int* in_sizes, int n_in,
                              void* d_out, int out_size, void* d_ws, size_t ws_size,
                              hipStream_t stream) {
  const float* x = (const float*)d_in[0];     // [16384, 512]
  const float* e = (const float*)d_in[1];     // [8192, 512]
  float* out = (float*)d_out;

  char* ws = (char*)d_ws;
  char* xbt = ws;                                       // 16 MB
  char* ebt = ws + 16777216;                            // 8 MB
  float* ehs = (float*)(ws + 25165824);                 // 32 KB
  ull_t* ppu = (ull_t*)(ws + 25198592);                 // 8 MB (N_*64 ull)
  float* pps2 = (float*)(ws + 33587200);                // 4 MB (N_*64 float)

  conv_all<<<1536, 256, 0, stream>>>(x, e, xbt, ebt, ehs);
  dist_mfma<<<dim3(128, 64), 256, 0, stream>>>(xbt, ebt, ehs, ppu, pps2);
  finalize<<<4096, 256, 0, stream>>>(x, e, ehs, ppu, pps2, out);
}

// Round 17
// 204.164 us; speedup vs baseline: 1.2792x; 1.0012x over previous
//
#include <hip/hip_runtime.h>
#include <cstddef>
#include <cstdint>

typedef unsigned short ushort_t;
typedef unsigned long long ull_t;
typedef __attribute__((ext_vector_type(8))) short short8;
typedef __attribute__((ext_vector_type(4))) float f32x4;

constexpr int D_ = 512, K_ = 8192, N_ = 16384;
constexpr float MARGIN = 0.75f;   // >= 2*eps of bf16-MFMA score error (max-tail ~0.45)

// RNE float->bf16 (data has no NaN)
__device__ __forceinline__ ushort_t f2bf(float f) {
  unsigned u = __float_as_uint(f);
  return (ushort_t)((u + 0x7FFFu + ((u >> 16) & 1u)) >> 16);
}
// order-preserving float->uint flip (max-compatible)
__device__ __forceinline__ unsigned flipf(float s) {
  unsigned u = __float_as_uint(s);
  return (u & 0x80000000u) ? ~u : (u | 0x80000000u);
}
__device__ __forceinline__ float unflipf(unsigned m) {
  unsigned u = (m & 0x80000000u) ? (m ^ 0x80000000u) : ~m;
  return __uint_as_float(u);
}
__device__ __forceinline__ ull_t umax64(ull_t a, ull_t b) { return a > b ? a : b; }
__device__ __forceinline__ ull_t umin64(ull_t a, ull_t b) { return a < b ? a : b; }

// -------- fused convert: x and e -> bf16 permuted layout (+ehs), coalesced reads --------
// dst layout: [tile][g(16)][kq(4)][r(128)] 16B chunks.
// blocks 0..1023: x (128 tiles x 8 rowgroups); blocks 1024..1535: e (64 tiles x 8 rowgroups)
__global__ __launch_bounds__(256) void conv_all(const float* __restrict__ x,
                                                const float* __restrict__ e,
                                                char* __restrict__ xbt, char* __restrict__ ebt,
                                                float* __restrict__ ehs) {
  const int g = threadIdx.x & 15, rr = threadIdx.x >> 4;
  if ((int)blockIdx.x < 1024) {
    const int tile = blockIdx.x >> 3, rg = blockIdx.x & 7;
    const int r = rg * 16 + rr;
    const float4* src = (const float4*)(x + ((size_t)(tile * 128 + r)) * D_ + g * 32);
    float4 f[8];
#pragma unroll
    for (int q = 0; q < 8; ++q) f[q] = src[q];
    char* dbase = xbt + (size_t)tile * 131072 + g * 8192 + r * 16;
#pragma unroll
    for (int kq = 0; kq < 4; ++kq) {
      float4 a = f[kq * 2], b = f[kq * 2 + 1];
      short8 v;
      v[0] = (short)f2bf(a.x); v[1] = (short)f2bf(a.y); v[2] = (short)f2bf(a.z); v[3] = (short)f2bf(a.w);
      v[4] = (short)f2bf(b.x); v[5] = (short)f2bf(b.y); v[6] = (short)f2bf(b.z); v[7] = (short)f2bf(b.w);
      *(short8*)(dbase + kq * 2048) = v;
    }
  } else {
    const int bid = blockIdx.x - 1024;
    const int tile = bid >> 3, rg = bid & 7;
    const int r = rg * 16 + rr;
    const int col = tile * 128 + r;
    const float4* src = (const float4*)(e + (size_t)col * D_ + g * 32);
    float4 f[8];
    float ss = 0.f;
#pragma unroll
    for (int q = 0; q < 8; ++q) {
      f[q] = src[q];
      ss += f[q].x * f[q].x + f[q].y * f[q].y + f[q].z * f[q].z + f[q].w * f[q].w;
    }
    char* dbase = ebt + (size_t)tile * 131072 + g * 8192 + r * 16;
#pragma unroll
    for (int kq = 0; kq < 4; ++kq) {
      float4 a = f[kq * 2], b = f[kq * 2 + 1];
      short8 v;
      v[0] = (short)f2bf(a.x); v[1] = (short)f2bf(a.y); v[2] = (short)f2bf(a.z); v[3] = (short)f2bf(a.w);
      v[4] = (short)f2bf(b.x); v[5] = (short)f2bf(b.y); v[6] = (short)f2bf(b.z); v[7] = (short)f2bf(b.w);
      *(short8*)(dbase + kq * 2048) = v;
    }
#pragma unroll
    for (int m = 1; m < 16; m <<= 1) ss += __shfl_xor(ss, m);
    if (g == 0) ehs[col] = 0.5f * ss;
  }
}

// -------- MFMA scoring: per (row, 128-col block) packed top-1 (score|invcol) + s2 --------
// grid (128,64); XCD-swizzled. Barrier-free streaming K-loop (fragments direct from L1/L2)
// with 2-DEEP software pipeline: g+1 and g+2's fragment loads are in flight while g's MFMA
// cluster issues (~160cyc cover ~= L2 round trip). Rotating 3-buffer registers, indices
// compile-time under full unroll. No inter-wave sync -> race-free by construction.
__global__ __launch_bounds__(256, 3) void dist_mfma(const char* __restrict__ xbt,
                                                    const char* __restrict__ ebt,
                                                    const float* __restrict__ ehs,
                                                    ull_t* __restrict__ ppu,
                                                    float* __restrict__ pps2) {
  __shared__ ull_t lp[256];     // cross-wave merge scratch only (3KB)
  __shared__ float ls2[256];
  const int tid = threadIdx.x, w = tid >> 6, l = tid & 63;
  // XCD-aware bijective remap: XCD k owns col-tiles [8k,8k+8), sweeps them innermost
  const int fid = blockIdx.x + blockIdx.y * 128;
  const int k8 = fid & 7, j = fid >> 3;
  const int by = k8 * 8 + (j & 7), bx = j >> 3;
  const int row0 = bx * 128, col0 = by * 128;
  const int wr = w >> 1, wc = w & 1;
  // per-lane fragment base addresses (contiguous 16B per lane in the permuted layout)
  const char* abase = xbt + (size_t)bx * 131072 + (l >> 4) * 2048 + wr * 1024 + (l & 15) * 16;
  const char* bbase = ebt + (size_t)by * 131072 + (l >> 4) * 2048 + wc * 1024 + (l & 15) * 16;

  short8 a[3][4], b[3][4];
#pragma unroll
  for (int s = 0; s < 2; ++s) {
#pragma unroll
    for (int i = 0; i < 4; ++i) a[s][i] = *(const short8*)(abase + s * 8192 + i * 256);
#pragma unroll
    for (int jj = 0; jj < 4; ++jj) b[s][jj] = *(const short8*)(bbase + s * 8192 + jj * 256);
  }

  f32x4 acc[4][4] = {};
#pragma unroll
  for (int g = 0; g < 16; ++g) {
    const int cur = g % 3;
    if (g + 2 < 16) {
      const int pf = (g + 2) % 3;
#pragma unroll
      for (int i = 0; i < 4; ++i)
        a[pf][i] = *(const short8*)(abase + (g + 2) * 8192 + i * 256);
#pragma unroll
      for (int jj = 0; jj < 4; ++jj)
        b[pf][jj] = *(const short8*)(bbase + (g + 2) * 8192 + jj * 256);
    }
    __builtin_amdgcn_s_setprio(1);
#pragma unroll
    for (int i = 0; i < 4; ++i)
#pragma unroll
      for (int jj = 0; jj < 4; ++jj)
        acc[i][jj] = __builtin_amdgcn_mfma_f32_16x16x32_bf16(a[cur][i], b[cur][jj], acc[i][jj], 0, 0, 0);
    __builtin_amdgcn_s_setprio(0);
  }

  // ---- epilogue (f32/u32 three-phase; no u64 until the final pack) ----
  float eh[4];
  unsigned ic[4];
#pragma unroll
  for (int jj = 0; jj < 4; ++jj) {
    int col = col0 + wc * 64 + jj * 16 + (l & 15);
    eh[jj] = ehs[col];
    ic[jj] = 0xFFFFFFFFu - (unsigned)col;   // larger == smaller col on score tie; never 0
  }
#pragma unroll
  for (int i = 0; i < 4; ++i)
#pragma unroll
    for (int jj = 0; jj < 4; ++jj)
#pragma unroll
      for (int r = 0; r < 4; ++r)
        acc[i][jj][r] -= eh[jj];

  // Phase A: row max (all-reduce over the 16 col-lanes)
  float mx[4][4];
#pragma unroll
  for (int i = 0; i < 4; ++i)
#pragma unroll
    for (int r = 0; r < 4; ++r)
      mx[i][r] = fmaxf(fmaxf(acc[i][0][r], acc[i][1][r]), fmaxf(acc[i][2][r], acc[i][3][r]));
#pragma unroll
  for (int m = 1; m < 16; m <<= 1)
#pragma unroll
    for (int i = 0; i < 4; ++i)
#pragma unroll
      for (int r = 0; r < 4; ++r)
        mx[i][r] = fmaxf(mx[i][r], __shfl_xor(mx[i][r], m));

  // Phase B: index (max inverted-col among elements equal to max)
  unsigned ii[4][4];
#pragma unroll
  for (int i = 0; i < 4; ++i)
#pragma unroll
    for (int r = 0; r < 4; ++r) {
      unsigned t0 = (acc[i][0][r] == mx[i][r]) ? ic[0] : 0u;
      unsigned t1 = (acc[i][1][r] == mx[i][r]) ? ic[1] : 0u;
      unsigned t2 = (acc[i][2][r] == mx[i][r]) ? ic[2] : 0u;
      unsigned t3 = (acc[i][3][r] == mx[i][r]) ? ic[3] : 0u;
      unsigned u01 = t0 > t1 ? t0 : t1, u23 = t2 > t3 ? t2 : t3;
      ii[i][r] = u01 > u23 ? u01 : u23;
    }
#pragma unroll
  for (int m = 1; m < 16; m <<= 1)
#pragma unroll
    for (int i = 0; i < 4; ++i)
#pragma unroll
      for (int r = 0; r < 4; ++r) {
        unsigned o = __shfl_xor(ii[i][r], m);
        ii[i][r] = ii[i][r] > o ? ii[i][r] : o;
      }

  // Phase C: s2 = max excluding exactly the chosen instance (ties -> s2 == max -> overflow)
  float s2[4][4];
#pragma unroll
  for (int i = 0; i < 4; ++i)
#pragma unroll
    for (int r = 0; r < 4; ++r) {
      float t0 = (ic[0] == ii[i][r]) ? -3e38f : acc[i][0][r];
      float t1 = (ic[1] == ii[i][r]) ? -3e38f : acc[i][1][r];
      float t2 = (ic[2] == ii[i][r]) ? -3e38f : acc[i][2][r];
      float t3 = (ic[3] == ii[i][r]) ? -3e38f : acc[i][3][r];
      s2[i][r] = fmaxf(fmaxf(t0, t1), fmaxf(t2, t3));
    }
#pragma unroll
  for (int m = 1; m < 16; m <<= 1)
#pragma unroll
    for (int i = 0; i < 4; ++i)
#pragma unroll
      for (int r = 0; r < 4; ++r)
        s2[i][r] = fmaxf(s2[i][r], __shfl_xor(s2[i][r], m));

  // owner-lane selection (compile-time indices only)
  const int c = l & 15, g16 = l >> 4;
  float fs1 = -3e38f, fs2 = -3e38f;
  unsigned fii = 0;
#pragma unroll
  for (int i = 0; i < 4; ++i) {
    if ((c >> 2) == i) {
      int rsel = c & 3;
      fs1 = (rsel == 0) ? mx[i][0] : (rsel == 1) ? mx[i][1] : (rsel == 2) ? mx[i][2] : mx[i][3];
      fii = (rsel == 0) ? ii[i][0] : (rsel == 1) ? ii[i][1] : (rsel == 2) ? ii[i][2] : ii[i][3];
      fs2 = (rsel == 0) ? s2[i][0] : (rsel == 1) ? s2[i][1] : (rsel == 2) ? s2[i][2] : s2[i][3];
    }
  }
  ull_t fp = ((ull_t)flipf(fs1) << 32) | fii;
  const int rib = wr * 64 + (c >> 2) * 16 + g16 * 4 + (c & 3);   // owned row in [0,128)

  // cross-wave (wc) merge via LDS
  lp[wc * 128 + rib] = fp; ls2[wc * 128 + rib] = fs2;
  __syncthreads();
  if (wc == 0) {
    ull_t op = lp[128 + rib];
    float os2 = ls2[128 + rib];
    ull_t lo = umin64(fp, op);
    fs2 = fmaxf(fmaxf(fs2, os2), unflipf((unsigned)(lo >> 32)));
    fp = umax64(fp, op);
    ppu[(size_t)(row0 + rib) * 64 + by] = fp;
    pps2[(size_t)(row0 + rib) * 64 + by] = fs2;
  }
}

// -------- finalize: combine + in-wave exact rescore + gather, one wave per row --------
__global__ __launch_bounds__(256) void finalize(const float* __restrict__ x,
                                                const float* __restrict__ embed,
                                                const float* __restrict__ ehs,
                                                const ull_t* __restrict__ ppu,
                                                const float* __restrict__ pps2,
                                                float* __restrict__ out) {
  const int row = (blockIdx.x * 256 + threadIdx.x) >> 6;
  const int l = threadIdx.x & 63;
  ull_t p = ppu[(size_t)row * 64 + l];
  float s2 = pps2[(size_t)row * 64 + l];
  ull_t gp = p;
#pragma unroll
  for (int m = 1; m < 64; m <<= 1) gp = umax64(gp, __shfl_xor(gp, m));
  float gs = unflipf((unsigned)(gp >> 32));
  float t = gs - MARGIN;
  bool cand = (unflipf((unsigned)(p >> 32)) >= t);
  bool ovf = (s2 >= t);
  ull_t b1 = __ballot(cand);
  ull_t b2 = __ballot(ovf);
  int idx;
  if (__popcll(b1) == 1 && b2 == 0ull) {
    // provably exact: every other col's fp32 score < gs - MARGIN + eps <= winner's fp32 score
    idx = (int)(0xFFFFFFFFu - (unsigned)(gp & 0xFFFFFFFFu));
  } else {
    const float4* xr4 = (const float4*)(x + (size_t)row * D_ + l * 8);
    float4 xa = xr4[0], xc = xr4[1];
    ull_t best = 0ull;
    ull_t bb = b1;
    while (bb) {                       // exact-score each candidate block-top-1 col
      int b = (int)__builtin_ctzll(bb);
      bb &= bb - 1;
      ull_t pb = __shfl(p, b);
      int col = (int)(0xFFFFFFFFu - (unsigned)(pb & 0xFFFFFFFFu));
      const float4* er4 = (const float4*)(embed + (size_t)col * D_ + l * 8);
      float4 ea = er4[0], ec = er4[1];
      float s = xa.x * ea.x + xa.y * ea.y + xa.z * ea.z + xa.w * ea.w
              + xc.x * ec.x + xc.y * ec.y + xc.z * ec.z + xc.w * ec.w;
#pragma unroll
      for (int m = 1; m < 64; m <<= 1) s += __shfl_xor(s, m);
      s -= ehs[col];
      best = umax64(best, ((ull_t)flipf(s) << 32) | (0xFFFFFFFFu - (unsigned)col));
    }
    while (b2) {                       // full exact scan of s2-overflow blocks (rare)
      int b = (int)__builtin_ctzll(b2);
      b2 &= b2 - 1;
      int c0 = b * 128;
      const float* xr = x + (size_t)row * D_;
      const float* e0p = embed + (size_t)(c0 + l) * D_;
      const float* e1p = embed + (size_t)(c0 + 64 + l) * D_;
      float a0 = 0.f, a1 = 0.f;
      for (int d = 0; d < D_; d += 4) {
        float4 xv = *(const float4*)(xr + d);
        float4 v0 = *(const float4*)(e0p + d);
        float4 v1 = *(const float4*)(e1p + d);
        a0 = fmaf(v0.x, xv.x, fmaf(v0.y, xv.y, fmaf(v0.z, xv.z, fmaf(v0.w, xv.w, a0))));
        a1 = fmaf(v1.x, xv.x, fmaf(v1.y, xv.y, fmaf(v1.z, xv.z, fmaf(v1.w, xv.w, a1))));
      }
      float s0 = a0 - ehs[c0 + l];
      float s1 = a1 - ehs[c0 + 64 + l];
      ull_t p0 = ((ull_t)flipf(s0) << 32) | (0xFFFFFFFFu - (unsigned)(c0 + l));
      ull_t p1 = ((ull_t)flipf(s1) << 32) | (0xFFFFFFFFu - (unsigned)(c0 + 64 + l));
      ull_t pk = umax64(p0, p1);
#pragma unroll
      for (int m = 1; m < 64; m <<= 1) pk = umax64(pk, __shfl_xor(pk, m));
      best = umax64(best, pk);
    }
    idx = (int)(0xFFFFFFFFu - (unsigned)(best & 0xFFFFFFFFu));
  }
  const float4* src = (const float4*)(embed + (size_t)idx * D_);
  float4* dst = (float4*)(out + (size_t)row * D_);
  dst[l] = src[l];
  dst[l + 64] = src[l + 64];
  if (l == 0) out[(size_t)N_ * D_ + row] = (float)idx;
}

extern "C" void kernel_launch(void* const* d_in, const int* in_sizes, int n_in,
                              void* d_out, int out_size, void* d_ws, size_t ws_size,
                              hipStream_t stream) {
  const float* x = (const float*)d_in[0];     // [16384, 512]
  const float* e = (const float*)d_in[1];     // [8192, 512]
  float* out = (float*)d_out;

  char* ws = (char*)d_ws;
  char* xbt = ws;                                       // 16 MB
  char* ebt = ws + 16777216;                            // 8 MB
  float* ehs = (float*)(ws + 25165824);                 // 32 KB
  ull_t* ppu = (ull_t*)(ws + 25198592);                 // 8 MB (N_*64 ull)
  float* pps2 = (float*)(ws + 33587200);                // 4 MB (N_*64 float)

  conv_all<<<1536, 256, 0, stream>>>(x, e, xbt, ebt, ehs);
  dist_mfma<<<dim3(128, 64), 256, 0, stream>>>(xbt, ebt, ehs, ppu, pps2);
  finalize<<<4096, 256, 0, stream>>>(x, e, ehs, ppu, pps2, out);
}